// Round 6
// baseline (520.116 us; speedup 1.0000x reference)
//
#include <hip/hip_runtime.h>
#include <hip/hip_fp16.h>

#define NNODES 100000
#define NEDGES 1600000
#define DIM 128
#define NB ((NNODES + 63) / 64)          // 1563 buckets of 64 nodes
#define NCH 128                          // scatter blocks / edge chunks
#define CHUNK ((NEDGES + NCH - 1) / NCH) // 12500 edges per chunk
#define EBUF 2560                        // per-bucket LDS edge capacity (mean 1024, max ~1300)

__device__ __forceinline__ float leaky02(float t) { return t > 0.f ? t : 0.2f * t; }

union H8u { uint2 u; __half2 h[2]; };

// ============ GEMM + attention dots, fp16 H out =====================
__global__ __launch_bounds__(256) void gemm_dots(const float* __restrict__ X,
                                                 const float* __restrict__ W,
                                                 const float* __restrict__ as_,
                                                 const float* __restrict__ ad_,
                                                 __half* __restrict__ H,
                                                 float* __restrict__ s,
                                                 float* __restrict__ d, int n) {
    __shared__ float xs[64][129];
    int t = threadIdx.x;
    int brow = blockIdx.x * 64;
    for (int i = t; i < 64 * 32; i += 256) {
        int r = i >> 5, c4 = (i & 31) * 4;
        int gr = brow + r;
        float4 v = (gr < n) ? *(const float4*)(X + (size_t)gr * 128 + c4)
                            : make_float4(0.f, 0.f, 0.f, 0.f);
        xs[r][c4] = v.x; xs[r][c4 + 1] = v.y; xs[r][c4 + 2] = v.z; xs[r][c4 + 3] = v.w;
    }
    __syncthreads();
    int r0 = (t >> 5) * 8;
    int c0 = (t & 31) * 4;
    float acc[8][4] = {};
#pragma unroll 2
    for (int k = 0; k < 128; ++k) {
        float4 wv = *(const float4*)(W + k * 128 + c0);
#pragma unroll
        for (int r = 0; r < 8; ++r) {
            float xr = xs[r0 + r][k];
            acc[r][0] += xr * wv.x;
            acc[r][1] += xr * wv.y;
            acc[r][2] += xr * wv.z;
            acc[r][3] += xr * wv.w;
        }
    }
    float as0 = as_[c0], as1 = as_[c0 + 1], as2 = as_[c0 + 2], as3 = as_[c0 + 3];
    float ad0 = ad_[c0], ad1 = ad_[c0 + 1], ad2 = ad_[c0 + 2], ad3 = ad_[c0 + 3];
    float sp[8], dp[8];
#pragma unroll
    for (int r = 0; r < 8; ++r) {
        int gr = brow + r0 + r;
        if (gr < n) {
            H8u pk;
            pk.h[0] = __floats2half2_rn(acc[r][0], acc[r][1]);
            pk.h[1] = __floats2half2_rn(acc[r][2], acc[r][3]);
            *(uint2*)(H + (size_t)gr * 128 + c0) = pk.u;
        }
        sp[r] = acc[r][0] * as0 + acc[r][1] * as1 + acc[r][2] * as2 + acc[r][3] * as3;
        dp[r] = acc[r][0] * ad0 + acc[r][1] * ad1 + acc[r][2] * ad2 + acc[r][3] * ad3;
    }
#pragma unroll
    for (int off = 16; off; off >>= 1)
#pragma unroll
        for (int r = 0; r < 8; ++r) {
            sp[r] += __shfl_xor(sp[r], off);
            dp[r] += __shfl_xor(dp[r], off);
        }
    if ((t & 31) == 0)
#pragma unroll
        for (int r = 0; r < 8; ++r) {
            int gr = brow + r0 + r;
            if (gr < n) { s[gr] = sp[r]; d[gr] = dp[r]; }
        }
}

// ============ bucket-sort CSR build (no global atomics) =============
// pass 1: per-block LDS histogram over NB buckets -> blockcounts[bin][blk]
__global__ __launch_bounds__(512) void bucket_count(const int* __restrict__ dst,
                                                    int* __restrict__ blockcounts) {
    __shared__ int hist[NB];
    int b = blockIdx.x, t = threadIdx.x;
    for (int i = t; i < NB; i += 512) hist[i] = 0;
    __syncthreads();
    int e0 = b * CHUNK, e1 = min(NEDGES, e0 + CHUNK);
    for (int e = e0 + t; e < e1; e += 512)
        atomicAdd(&hist[dst[e] >> 6], 1);
    __syncthreads();
    for (int i = t; i < NB; i += 512)
        blockcounts[i * NCH + b] = hist[i];
}

// pass 2: one block. bucket bases + per-(bin,block) start offsets.
__global__ __launch_bounds__(1024) void bucket_scan(int* __restrict__ blockcounts,
                                                    int* __restrict__ bbase) {
    __shared__ int ts[2][1024];
    int t = threadIdx.x;
    int b0 = t * 2;
    int c0 = 0, c1 = 0;
    if (b0 < NB)     for (int b = 0; b < NCH; ++b) c0 += blockcounts[b0 * NCH + b];
    if (b0 + 1 < NB) for (int b = 0; b < NCH; ++b) c1 += blockcounts[(b0 + 1) * NCH + b];
    int sum = c0 + c1;
    ts[0][t] = sum;
    __syncthreads();
    int sb = 0;
    for (int off = 1; off < 1024; off <<= 1) {
        int v = ts[sb][t] + ((t >= off) ? ts[sb][t - off] : 0);
        ts[sb ^ 1][t] = v;
        sb ^= 1;
        __syncthreads();
    }
    int excl = ts[sb][t] - sum;
    if (b0 < NB) {
        bbase[b0] = excl;
        int run = excl;
        for (int b = 0; b < NCH; ++b) {
            int tmp = blockcounts[b0 * NCH + b];
            blockcounts[b0 * NCH + b] = run;
            run += tmp;
        }
        if (b0 + 1 < NB) {
            bbase[b0 + 1] = run;
            int run1 = run;
            for (int b = 0; b < NCH; ++b) {
                int tmp = blockcounts[(b0 + 1) * NCH + b];
                blockcounts[(b0 + 1) * NCH + b] = run1;
                run1 += tmp;
            }
        }
    }
    if (t == 1023) bbase[NB] = ts[sb][1023];   // == NEDGES
}

// pass 3: scatter edges into bucket-sorted packed array via LDS cursors
__global__ __launch_bounds__(512) void bucket_scatter(const int* __restrict__ src,
                                                      const int* __restrict__ dst,
                                                      const int* __restrict__ blockcounts,
                                                      int* __restrict__ packed) {
    __shared__ int cur[NB];
    int b = blockIdx.x, t = threadIdx.x;
    for (int i = t; i < NB; i += 512) cur[i] = blockcounts[i * NCH + b];
    __syncthreads();
    int e0 = b * CHUNK, e1 = min(NEDGES, e0 + CHUNK);
    for (int e = e0 + t; e < e1; e += 512) {
        int dv = dst[e];
        int bin = dv >> 6;
        int p = atomicAdd(&cur[bin], 1);              // LDS atomic
        packed[p] = ((dv & 63) << 17) | src[e];       // src < 2^17
    }
}

// pass 4: per-bucket local count/scan -> rowptr + csr_src (coalesced)
__global__ __launch_bounds__(256) void bucket_csr(const int* __restrict__ packed,
                                                  const int* __restrict__ bbase,
                                                  int* __restrict__ rowptr,
                                                  int* __restrict__ csr_src) {
    __shared__ int ebuf[EBUF];
    __shared__ int hist[64], cur[64];
    int i = blockIdx.x, t = threadIdx.x;
    int base = bbase[i], cnt = bbase[i + 1] - base;
    bool inl = (cnt <= EBUF);
    if (inl) for (int j = t; j < cnt; j += 256) ebuf[j] = packed[base + j];
    if (t < 64) hist[t] = 0;
    __syncthreads();
    for (int j = t; j < cnt; j += 256) {
        int v = inl ? ebuf[j] : packed[base + j];
        atomicAdd(&hist[v >> 17], 1);
    }
    __syncthreads();
    if (t < 64) {
        int h = hist[t];
        int incl = h;
#pragma unroll
        for (int off = 1; off < 64; off <<= 1) {
            int u = __shfl_up(incl, off, 64);
            if (t >= off) incl += u;
        }
        int ex = incl - h;
        cur[t] = ex;
        int node = i * 64 + t;
        if (node <= NNODES) rowptr[node] = base + ex;  // node==N lands on E exactly
    }
    __syncthreads();
    for (int j = t; j < cnt; j += 256) {
        int v = inl ? ebuf[j] : packed[base + j];
        int off = atomicAdd(&cur[v >> 17], 1);
        csr_src[base + off] = v & 0x1FFFF;
    }
}

// ============ fused gather: softmax + aggregate + bias + relu (+classifier)
template <bool LAST>
__global__ __launch_bounds__(256) void gat_gather(const int* __restrict__ rowptr,
                                                  const int* __restrict__ csr,
                                                  const float* __restrict__ s,
                                                  const float* __restrict__ d,
                                                  const __half* __restrict__ H,
                                                  const float* __restrict__ bias,
                                                  const float* __restrict__ Wc,
                                                  const float* __restrict__ bc,
                                                  float* __restrict__ A,
                                                  float* __restrict__ out, int n) {
    int node = blockIdx.x * 4 + (threadIdx.x >> 6);
    if (node >= n) return;
    int lane = threadIdx.x & 63;
    int half = lane >> 5;
    int pos  = lane & 31;
    int base = rowptr[node];
    int deg  = rowptr[node + 1] - base;
    float dnode = d[node];
    float snode = s[node];

    float4 acc = make_float4(0.f, 0.f, 0.f, 0.f);
    float denom;

    if (deg < 64) {
        // ---- fast path: deg edges + self loop fit in one wave
        int cnt = deg + 1;
        int si  = (lane < deg) ? csr[base + lane] : node;
        float sv = (lane < deg) ? s[si] : snode;
        float lv = leaky02(sv + dnode);
        float lm = (lane < cnt) ? lv : -1e30f;
#pragma unroll
        for (int off = 32; off; off >>= 1) lm = fmaxf(lm, __shfl_xor(lm, off));
        float w = (lane < cnt) ? expf(lv - lm) : 0.f;
        denom = w;
#pragma unroll
        for (int off = 32; off; off >>= 1) denom += __shfl_xor(denom, off);

        int cnt16 = (cnt + 15) & ~15;
        for (int j = 0; j < cnt16; j += 16) {
            float wk[8]; int sk[8];
#pragma unroll
            for (int k = 0; k < 8; ++k) {
                int ii = j + 2 * k + half;
                wk[k] = __shfl(w, ii);
                sk[k] = __shfl(si, ii);
            }
            H8u hv[8];
#pragma unroll
            for (int k = 0; k < 8; ++k)
                hv[k].u = *(const uint2*)(H + (size_t)sk[k] * 128 + pos * 4);
#pragma unroll
            for (int k = 0; k < 8; ++k) {
                float2 a01 = __half22float2(hv[k].h[0]);
                float2 a23 = __half22float2(hv[k].h[1]);
                acc.x += wk[k] * a01.x;
                acc.y += wk[k] * a01.y;
                acc.z += wk[k] * a23.x;
                acc.w += wk[k] * a23.y;
            }
        }
    } else {
        // ---- general path (deg >= 64)
        float m = -1e30f;
        for (int c = 0; c <= deg; c += 64) {
            int idx = c + lane;
            float lv = -1e30f;
            if (idx < deg)       lv = leaky02(s[csr[base + idx]] + dnode);
            else if (idx == deg) lv = leaky02(snode + dnode);
            m = fmaxf(m, lv);
        }
#pragma unroll
        for (int off = 32; off; off >>= 1) m = fmaxf(m, __shfl_xor(m, off));
        denom = 0.f;
        for (int c = 0; c <= deg; c += 64) {
            int idx = c + lane;
            int cnt = min(64, deg + 1 - c);
            int si = (idx < deg) ? csr[base + idx] : node;
            float w = 0.f;
            if (idx < deg)       w = expf(leaky02(s[si] + dnode) - m);
            else if (idx == deg) w = expf(leaky02(snode + dnode) - m);
            denom += w;
            int cnt16 = (cnt + 15) & ~15;
            for (int j = 0; j < cnt16; j += 16) {
                float wk[8]; int sk[8];
#pragma unroll
                for (int k = 0; k < 8; ++k) {
                    int ii = j + 2 * k + half;
                    wk[k] = __shfl(w, ii);
                    sk[k] = __shfl(si, ii);
                }
                H8u hv[8];
#pragma unroll
                for (int k = 0; k < 8; ++k)
                    hv[k].u = *(const uint2*)(H + (size_t)sk[k] * 128 + pos * 4);
#pragma unroll
                for (int k = 0; k < 8; ++k) {
                    float2 a01 = __half22float2(hv[k].h[0]);
                    float2 a23 = __half22float2(hv[k].h[1]);
                    acc.x += wk[k] * a01.x;
                    acc.y += wk[k] * a01.y;
                    acc.z += wk[k] * a23.x;
                    acc.w += wk[k] * a23.y;
                }
            }
        }
#pragma unroll
        for (int off = 32; off; off >>= 1) denom += __shfl_xor(denom, off);
    }

    acc.x += __shfl_xor(acc.x, 32);
    acc.y += __shfl_xor(acc.y, 32);
    acc.z += __shfl_xor(acc.z, 32);
    acc.w += __shfl_xor(acc.w, 32);
    if (half == 0) {
        float inv = 1.f / denom;
        float4 o;
        o.x = fmaxf(acc.x * inv + bias[pos * 4 + 0], 0.f);
        o.y = fmaxf(acc.y * inv + bias[pos * 4 + 1], 0.f);
        o.z = fmaxf(acc.z * inv + bias[pos * 4 + 2], 0.f);
        o.w = fmaxf(acc.w * inv + bias[pos * 4 + 3], 0.f);
        if (!LAST) {
            *(float4*)(A + (size_t)node * 128 + pos * 4) = o;
        } else {
            float c0v = o.x * Wc[(pos * 4 + 0) * 2] + o.y * Wc[(pos * 4 + 1) * 2] +
                        o.z * Wc[(pos * 4 + 2) * 2] + o.w * Wc[(pos * 4 + 3) * 2];
            float c1v = o.x * Wc[(pos * 4 + 0) * 2 + 1] + o.y * Wc[(pos * 4 + 1) * 2 + 1] +
                        o.z * Wc[(pos * 4 + 2) * 2 + 1] + o.w * Wc[(pos * 4 + 3) * 2 + 1];
#pragma unroll
            for (int off = 16; off; off >>= 1) {
                c0v += __shfl_xor(c0v, off);
                c1v += __shfl_xor(c1v, off);
            }
            if (pos == 0) {
                out[(size_t)node * 2 + 0] = c0v + bc[0];
                out[(size_t)node * 2 + 1] = c1v + bc[1];
            }
        }
    }
}

extern "C" void kernel_launch(void* const* d_in, const int* in_sizes, int n_in,
                              void* d_out, int out_size, void* d_ws, size_t ws_size,
                              hipStream_t stream) {
    const float* x   = (const float*)d_in[0];
    const int*   ei  = (const int*)d_in[1];
    const int*   src = ei;            // edge_index[0], length E
    const int*   dst = ei + NEDGES;   // edge_index[1], length E
    const float* Ws[3]  = {(const float*)d_in[2], (const float*)d_in[6], (const float*)d_in[10]};
    const float* ass[3] = {(const float*)d_in[3], (const float*)d_in[7], (const float*)d_in[11]};
    const float* ads[3] = {(const float*)d_in[4], (const float*)d_in[8], (const float*)d_in[12]};
    const float* bs[3]  = {(const float*)d_in[5], (const float*)d_in[9], (const float*)d_in[13]};
    const float* Wc = (const float*)d_in[14];
    const float* bc = (const float*)d_in[15];
    float* out = (float*)d_out;

    const int n = NNODES;

    // ---- workspace (~92 MB): abuf f32 | s | d | h16 fp16 | int tail
    float*  abuf = (float*)d_ws;                    // N*128 f32
    float*  sbuf = abuf + (size_t)n * DIM;          // N
    float*  dbuf = sbuf + n;                        // N
    __half* h16  = (__half*)(dbuf + n);             // N*128 fp16
    int*    rowptr      = (int*)(h16 + (size_t)n * DIM);  // N+1
    int*    csr_src     = rowptr + n + 1;                 // E
    int*    packed      = csr_src + NEDGES;               // E
    int*    blockcounts = packed + NEDGES;                // NB*NCH
    int*    bbase       = blockcounts + NB * NCH;         // NB+1

    const int g64         = (n + 63) / 64;
    const int gather_grid = (n + 3) / 4;

    // ---- bucket-sort CSR build (once, reused by all 3 layers) ----
    bucket_count<<<NCH, 512, 0, stream>>>(dst, blockcounts);
    bucket_scan<<<1, 1024, 0, stream>>>(blockcounts, bbase);
    bucket_scatter<<<NCH, 512, 0, stream>>>(src, dst, blockcounts, packed);
    bucket_csr<<<NB, 256, 0, stream>>>(packed, bbase, rowptr, csr_src);

    // ---- 3 GAT layers ----
    const float* xin = x;
    for (int layer = 0; layer < 3; ++layer) {
        gemm_dots<<<g64, 256, 0, stream>>>(xin, Ws[layer], ass[layer], ads[layer],
                                           h16, sbuf, dbuf, n);
        if (layer == 2)
            gat_gather<true><<<gather_grid, 256, 0, stream>>>(
                rowptr, csr_src, sbuf, dbuf, h16, bs[layer], Wc, bc, abuf, out, n);
        else
            gat_gather<false><<<gather_grid, 256, 0, stream>>>(
                rowptr, csr_src, sbuf, dbuf, h16, bs[layer], Wc, bc, abuf, out, n);
        xin = abuf;
    }
}

// Round 7
// 440.190 us; speedup vs baseline: 1.1816x; 1.1816x over previous
//
#include <hip/hip_runtime.h>
#include <hip/hip_fp16.h>

#define NNODES 100000
#define NEDGES 1600000
#define DIM 128
#define NB ((NNODES + 63) / 64)          // 1563 buckets of 64 nodes
#define NCH 128                          // scatter blocks / edge chunks
#define CHUNK ((NEDGES + NCH - 1) / NCH) // 12500 edges per chunk
#define EBUF 2560                        // per-bucket LDS edge capacity (mean 1024)

__device__ __forceinline__ float leaky02(float t) { return t > 0.f ? t : 0.2f * t; }

union H8u { uint2 u; __half2 h[2]; };

// ============ GEMM + attention dots, fp16 H out =====================
__global__ __launch_bounds__(256) void gemm_dots(const float* __restrict__ X,
                                                 const float* __restrict__ W,
                                                 const float* __restrict__ as_,
                                                 const float* __restrict__ ad_,
                                                 __half* __restrict__ H,
                                                 float* __restrict__ s,
                                                 float* __restrict__ d, int n) {
    __shared__ float xs[64][129];
    int t = threadIdx.x;
    int brow = blockIdx.x * 64;
    for (int i = t; i < 64 * 32; i += 256) {
        int r = i >> 5, c4 = (i & 31) * 4;
        int gr = brow + r;
        float4 v = (gr < n) ? *(const float4*)(X + (size_t)gr * 128 + c4)
                            : make_float4(0.f, 0.f, 0.f, 0.f);
        xs[r][c4] = v.x; xs[r][c4 + 1] = v.y; xs[r][c4 + 2] = v.z; xs[r][c4 + 3] = v.w;
    }
    __syncthreads();
    int r0 = (t >> 5) * 8;
    int c0 = (t & 31) * 4;
    float acc[8][4] = {};
#pragma unroll 2
    for (int k = 0; k < 128; ++k) {
        float4 wv = *(const float4*)(W + k * 128 + c0);
#pragma unroll
        for (int r = 0; r < 8; ++r) {
            float xr = xs[r0 + r][k];
            acc[r][0] += xr * wv.x;
            acc[r][1] += xr * wv.y;
            acc[r][2] += xr * wv.z;
            acc[r][3] += xr * wv.w;
        }
    }
    float as0 = as_[c0], as1 = as_[c0 + 1], as2 = as_[c0 + 2], as3 = as_[c0 + 3];
    float ad0 = ad_[c0], ad1 = ad_[c0 + 1], ad2 = ad_[c0 + 2], ad3 = ad_[c0 + 3];
    float sp[8], dp[8];
#pragma unroll
    for (int r = 0; r < 8; ++r) {
        int gr = brow + r0 + r;
        if (gr < n) {
            H8u pk;
            pk.h[0] = __floats2half2_rn(acc[r][0], acc[r][1]);
            pk.h[1] = __floats2half2_rn(acc[r][2], acc[r][3]);
            *(uint2*)(H + (size_t)gr * 128 + c0) = pk.u;
        }
        sp[r] = acc[r][0] * as0 + acc[r][1] * as1 + acc[r][2] * as2 + acc[r][3] * as3;
        dp[r] = acc[r][0] * ad0 + acc[r][1] * ad1 + acc[r][2] * ad2 + acc[r][3] * ad3;
    }
#pragma unroll
    for (int off = 16; off; off >>= 1)
#pragma unroll
        for (int r = 0; r < 8; ++r) {
            sp[r] += __shfl_xor(sp[r], off);
            dp[r] += __shfl_xor(dp[r], off);
        }
    if ((t & 31) == 0)
#pragma unroll
        for (int r = 0; r < 8; ++r) {
            int gr = brow + r0 + r;
            if (gr < n) { s[gr] = sp[r]; d[gr] = dp[r]; }
        }
}

// ============ bucket-sort CSR build (no global atomics) =============
// pass 1: per-block LDS histogram over NB buckets -> blockcounts[bin][blk]
__global__ __launch_bounds__(512) void bucket_count(const int* __restrict__ dst,
                                                    int* __restrict__ blockcounts) {
    __shared__ int hist[NB];
    int b = blockIdx.x, t = threadIdx.x;
    for (int i = t; i < NB; i += 512) hist[i] = 0;
    __syncthreads();
    int e0 = b * CHUNK, e1 = min(NEDGES, e0 + CHUNK);
    for (int e = e0 + t; e < e1; e += 512)
        atomicAdd(&hist[dst[e] >> 6], 1);
    __syncthreads();
    for (int i = t; i < NB; i += 512)
        blockcounts[i * NCH + b] = hist[i];
}

// pass 2a: per-bucket exclusive scan over its NCH chunk counts (1 block/bucket)
__global__ __launch_bounds__(NCH) void bucket_scan_a(int* __restrict__ blockcounts,
                                                     int* __restrict__ btotal) {
    int bin = blockIdx.x, t = threadIdx.x;
    int v = blockcounts[bin * NCH + t];
    int incl = v;
#pragma unroll
    for (int off = 1; off < 64; off <<= 1) {
        int u = __shfl_up(incl, off, 64);
        if ((t & 63) >= off) incl += u;
    }
    __shared__ int wsum;
    if (t == 63) wsum = incl;
    __syncthreads();
    int excl = incl - v + ((t >= 64) ? wsum : 0);
    blockcounts[bin * NCH + t] = excl;
    if (t == NCH - 1) btotal[bin] = excl + v;
}

// pass 2b: one block scans bucket totals -> bbase[NB+1]
__global__ __launch_bounds__(1024) void bucket_scan_b(const int* __restrict__ btotal,
                                                      int* __restrict__ bbase) {
    __shared__ int ts[2][1024];
    int t = threadIdx.x;
    int b0 = t * 2;
    int c0 = (b0 < NB)     ? btotal[b0]     : 0;
    int c1 = (b0 + 1 < NB) ? btotal[b0 + 1] : 0;
    int sum = c0 + c1;
    ts[0][t] = sum;
    __syncthreads();
    int sb = 0;
    for (int off = 1; off < 1024; off <<= 1) {
        int v = ts[sb][t] + ((t >= off) ? ts[sb][t - off] : 0);
        ts[sb ^ 1][t] = v;
        sb ^= 1;
        __syncthreads();
    }
    int excl = ts[sb][t] - sum;
    if (b0 < NB)     bbase[b0]     = excl;
    if (b0 + 1 < NB) bbase[b0 + 1] = excl + c0;
    if (t == 1023) bbase[NB] = ts[sb][1023];   // == NEDGES
}

// pass 3: scatter edges into bucket-sorted packed array via LDS cursors
__global__ __launch_bounds__(512) void bucket_scatter(const int* __restrict__ src,
                                                      const int* __restrict__ dst,
                                                      const int* __restrict__ blockcounts,
                                                      const int* __restrict__ bbase,
                                                      int* __restrict__ packed) {
    __shared__ int cur[NB];
    int b = blockIdx.x, t = threadIdx.x;
    for (int i = t; i < NB; i += 512) cur[i] = bbase[i] + blockcounts[i * NCH + b];
    __syncthreads();
    int e0 = b * CHUNK, e1 = min(NEDGES, e0 + CHUNK);
    for (int e = e0 + t; e < e1; e += 512) {
        int dv = dst[e];
        int bin = dv >> 6;
        int p = atomicAdd(&cur[bin], 1);              // LDS atomic
        packed[p] = ((dv & 63) << 17) | src[e];       // src < 2^17
    }
}

// pass 4: per-bucket local count/scan -> rowptr + csr_src (coalesced)
__global__ __launch_bounds__(256) void bucket_csr(const int* __restrict__ packed,
                                                  const int* __restrict__ bbase,
                                                  int* __restrict__ rowptr,
                                                  int* __restrict__ csr_src) {
    __shared__ int ebuf[EBUF];
    __shared__ int hist[64], cur[64];
    int i = blockIdx.x, t = threadIdx.x;
    int base = bbase[i], cnt = bbase[i + 1] - base;
    bool inl = (cnt <= EBUF);
    if (inl) for (int j = t; j < cnt; j += 256) ebuf[j] = packed[base + j];
    if (t < 64) hist[t] = 0;
    __syncthreads();
    for (int j = t; j < cnt; j += 256) {
        int v = inl ? ebuf[j] : packed[base + j];
        atomicAdd(&hist[v >> 17], 1);
    }
    __syncthreads();
    if (t < 64) {
        int h = hist[t];
        int incl = h;
#pragma unroll
        for (int off = 1; off < 64; off <<= 1) {
            int u = __shfl_up(incl, off, 64);
            if (t >= off) incl += u;
        }
        int ex = incl - h;
        cur[t] = ex;
        int node = i * 64 + t;
        if (node <= NNODES) rowptr[node] = base + ex;
    }
    __syncthreads();
    for (int j = t; j < cnt; j += 256) {
        int v = inl ? ebuf[j] : packed[base + j];
        int off = atomicAdd(&cur[v >> 17], 1);
        csr_src[base + off] = v & 0x1FFFF;
    }
}

// ============ fused gather: softmax + aggregate + bias + relu (+classifier)
template <bool LAST>
__global__ __launch_bounds__(256) void gat_gather(const int* __restrict__ rowptr,
                                                  const int* __restrict__ csr,
                                                  const float* __restrict__ s,
                                                  const float* __restrict__ d,
                                                  const __half* __restrict__ H,
                                                  const float* __restrict__ bias,
                                                  const float* __restrict__ Wc,
                                                  const float* __restrict__ bc,
                                                  float* __restrict__ A,
                                                  float* __restrict__ out, int n) {
    int node = blockIdx.x * 4 + (threadIdx.x >> 6);
    if (node >= n) return;
    int lane = threadIdx.x & 63;
    int half = lane >> 5;
    int pos  = lane & 31;
    int base = rowptr[node];
    int deg  = rowptr[node + 1] - base;
    float dnode = d[node];
    float snode = s[node];

    float4 acc = make_float4(0.f, 0.f, 0.f, 0.f);
    float denom;

    if (deg < 64) {
        int cnt = deg + 1;
        int si  = (lane < deg) ? csr[base + lane] : node;
        float sv = (lane < deg) ? s[si] : snode;
        float lv = leaky02(sv + dnode);
        float lm = (lane < cnt) ? lv : -1e30f;
#pragma unroll
        for (int off = 32; off; off >>= 1) lm = fmaxf(lm, __shfl_xor(lm, off));
        float w = (lane < cnt) ? expf(lv - lm) : 0.f;
        denom = w;
#pragma unroll
        for (int off = 32; off; off >>= 1) denom += __shfl_xor(denom, off);

        int cnt16 = (cnt + 15) & ~15;
        for (int j = 0; j < cnt16; j += 16) {
            float wk[8]; int sk[8];
#pragma unroll
            for (int k = 0; k < 8; ++k) {
                int ii = j + 2 * k + half;
                wk[k] = __shfl(w, ii);
                sk[k] = __shfl(si, ii);
            }
            H8u hv[8];
#pragma unroll
            for (int k = 0; k < 8; ++k)
                hv[k].u = *(const uint2*)(H + (size_t)sk[k] * 128 + pos * 4);
#pragma unroll
            for (int k = 0; k < 8; ++k) {
                float2 a01 = __half22float2(hv[k].h[0]);
                float2 a23 = __half22float2(hv[k].h[1]);
                acc.x += wk[k] * a01.x;
                acc.y += wk[k] * a01.y;
                acc.z += wk[k] * a23.x;
                acc.w += wk[k] * a23.y;
            }
        }
    } else {
        float m = -1e30f;
        for (int c = 0; c <= deg; c += 64) {
            int idx = c + lane;
            float lv = -1e30f;
            if (idx < deg)       lv = leaky02(s[csr[base + idx]] + dnode);
            else if (idx == deg) lv = leaky02(snode + dnode);
            m = fmaxf(m, lv);
        }
#pragma unroll
        for (int off = 32; off; off >>= 1) m = fmaxf(m, __shfl_xor(m, off));
        denom = 0.f;
        for (int c = 0; c <= deg; c += 64) {
            int idx = c + lane;
            int cnt = min(64, deg + 1 - c);
            int si = (idx < deg) ? csr[base + idx] : node;
            float w = 0.f;
            if (idx < deg)       w = expf(leaky02(s[si] + dnode) - m);
            else if (idx == deg) w = expf(leaky02(snode + dnode) - m);
            denom += w;
            int cnt16 = (cnt + 15) & ~15;
            for (int j = 0; j < cnt16; j += 16) {
                float wk[8]; int sk[8];
#pragma unroll
                for (int k = 0; k < 8; ++k) {
                    int ii = j + 2 * k + half;
                    wk[k] = __shfl(w, ii);
                    sk[k] = __shfl(si, ii);
                }
                H8u hv[8];
#pragma unroll
                for (int k = 0; k < 8; ++k)
                    hv[k].u = *(const uint2*)(H + (size_t)sk[k] * 128 + pos * 4);
#pragma unroll
                for (int k = 0; k < 8; ++k) {
                    float2 a01 = __half22float2(hv[k].h[0]);
                    float2 a23 = __half22float2(hv[k].h[1]);
                    acc.x += wk[k] * a01.x;
                    acc.y += wk[k] * a01.y;
                    acc.z += wk[k] * a23.x;
                    acc.w += wk[k] * a23.y;
                }
            }
        }
#pragma unroll
        for (int off = 32; off; off >>= 1) denom += __shfl_xor(denom, off);
    }

    acc.x += __shfl_xor(acc.x, 32);
    acc.y += __shfl_xor(acc.y, 32);
    acc.z += __shfl_xor(acc.z, 32);
    acc.w += __shfl_xor(acc.w, 32);
    if (half == 0) {
        float inv = 1.f / denom;
        float4 o;
        o.x = fmaxf(acc.x * inv + bias[pos * 4 + 0], 0.f);
        o.y = fmaxf(acc.y * inv + bias[pos * 4 + 1], 0.f);
        o.z = fmaxf(acc.z * inv + bias[pos * 4 + 2], 0.f);
        o.w = fmaxf(acc.w * inv + bias[pos * 4 + 3], 0.f);
        if (!LAST) {
            *(float4*)(A + (size_t)node * 128 + pos * 4) = o;
        } else {
            float c0v = o.x * Wc[(pos * 4 + 0) * 2] + o.y * Wc[(pos * 4 + 1) * 2] +
                        o.z * Wc[(pos * 4 + 2) * 2] + o.w * Wc[(pos * 4 + 3) * 2];
            float c1v = o.x * Wc[(pos * 4 + 0) * 2 + 1] + o.y * Wc[(pos * 4 + 1) * 2 + 1] +
                        o.z * Wc[(pos * 4 + 2) * 2 + 1] + o.w * Wc[(pos * 4 + 3) * 2 + 1];
#pragma unroll
            for (int off = 16; off; off >>= 1) {
                c0v += __shfl_xor(c0v, off);
                c1v += __shfl_xor(c1v, off);
            }
            if (pos == 0) {
                out[(size_t)node * 2 + 0] = c0v + bc[0];
                out[(size_t)node * 2 + 1] = c1v + bc[1];
            }
        }
    }
}

extern "C" void kernel_launch(void* const* d_in, const int* in_sizes, int n_in,
                              void* d_out, int out_size, void* d_ws, size_t ws_size,
                              hipStream_t stream) {
    const float* x   = (const float*)d_in[0];
    const int*   ei  = (const int*)d_in[1];
    const int*   src = ei;            // edge_index[0], length E
    const int*   dst = ei + NEDGES;   // edge_index[1], length E
    const float* Ws[3]  = {(const float*)d_in[2], (const float*)d_in[6], (const float*)d_in[10]};
    const float* ass[3] = {(const float*)d_in[3], (const float*)d_in[7], (const float*)d_in[11]};
    const float* ads[3] = {(const float*)d_in[4], (const float*)d_in[8], (const float*)d_in[12]};
    const float* bs[3]  = {(const float*)d_in[5], (const float*)d_in[9], (const float*)d_in[13]};
    const float* Wc = (const float*)d_in[14];
    const float* bc = (const float*)d_in[15];
    float* out = (float*)d_out;

    const int n = NNODES;

    // ---- workspace (~92 MB): abuf f32 | s | d | h16 fp16 | int tail
    float*  abuf = (float*)d_ws;                    // N*128 f32
    float*  sbuf = abuf + (size_t)n * DIM;          // N
    float*  dbuf = sbuf + n;                        // N
    __half* h16  = (__half*)(dbuf + n);             // N*128 fp16
    int*    rowptr      = (int*)(h16 + (size_t)n * DIM);  // N+1
    int*    csr_src     = rowptr + n + 1;                 // E
    int*    packed      = csr_src + NEDGES;               // E
    int*    blockcounts = packed + NEDGES;                // NB*NCH
    int*    bbase       = blockcounts + NB * NCH;         // NB+1
    int*    btotal      = bbase + NB + 1;                 // NB

    const int g64         = (n + 63) / 64;
    const int gather_grid = (n + 3) / 4;

    // ---- bucket-sort CSR build (once, reused by all 3 layers) ----
    bucket_count<<<NCH, 512, 0, stream>>>(dst, blockcounts);
    bucket_scan_a<<<NB, NCH, 0, stream>>>(blockcounts, btotal);
    bucket_scan_b<<<1, 1024, 0, stream>>>(btotal, bbase);
    bucket_scatter<<<NCH, 512, 0, stream>>>(src, dst, blockcounts, bbase, packed);
    bucket_csr<<<NB, 256, 0, stream>>>(packed, bbase, rowptr, csr_src);

    // ---- 3 GAT layers ----
    const float* xin = x;
    for (int layer = 0; layer < 3; ++layer) {
        gemm_dots<<<g64, 256, 0, stream>>>(xin, Ws[layer], ass[layer], ads[layer],
                                           h16, sbuf, dbuf, n);
        if (layer == 2)
            gat_gather<true><<<gather_grid, 256, 0, stream>>>(
                rowptr, csr_src, sbuf, dbuf, h16, bs[layer], Wc, bc, abuf, out, n);
        else
            gat_gather<false><<<gather_grid, 256, 0, stream>>>(
                rowptr, csr_src, sbuf, dbuf, h16, bs[layer], Wc, bc, abuf, out, n);
        xin = abuf;
    }
}

// Round 8
// 423.705 us; speedup vs baseline: 1.2275x; 1.0389x over previous
//
#include <hip/hip_runtime.h>
#include <hip/hip_fp16.h>

#define NNODES 100000
#define NEDGES 1600000
#define DIM 128
#define NB ((NNODES + 63) / 64)          // 1563 buckets of 64 nodes
#define NCH 128                          // scatter blocks / edge chunks
#define CHUNK ((NEDGES + NCH - 1) / NCH) // 12500 edges per chunk
#define EBUF 2560                        // per-bucket LDS edge capacity
#define LSTR 136                         // padded LDS stride (halfs): 2-way-conflict-free

typedef _Float16 f16x8 __attribute__((ext_vector_type(8)));
typedef float f32x4 __attribute__((ext_vector_type(4)));

__device__ __forceinline__ float leaky02(float t) { return t > 0.f ? t : 0.2f * t; }

union H8u { uint2 u; __half2 h[2]; };

// ============ MFMA fp16 GEMM + fused attention dots ==================
// block: 64 rows x 128 cols, 4 waves; wave: 16 rows x 128 cols.
// A-frag: lane holds A[l&15][kk + (l>>4)*8 + j]  (8 consecutive k)
// B-frag: lane holds W[kk + (l>>4)*8 + j][ct*16 + (l&15)] via Wt LDS
// C:      acc[ct][j] = H[(l>>4)*4 + j][ct*16 + (l&15)]   (m89-verified)
template <bool XF16>
__global__ __launch_bounds__(256) void gemm_mfma(const float* __restrict__ X,
                                                 const __half* __restrict__ X16,
                                                 const float* __restrict__ W,
                                                 const float* __restrict__ as_,
                                                 const float* __restrict__ ad_,
                                                 __half* __restrict__ H,
                                                 float* __restrict__ s,
                                                 float* __restrict__ d, int n) {
    __shared__ __half As[64][LSTR];
    __shared__ __half Wt[128][LSTR];
    int t = threadIdx.x;
    int brow = blockIdx.x * 64;

    // stage A-tile (fp16)
    if (XF16) {
        for (int i = t; i < 64 * 16; i += 256) {
            int r = i >> 4, c8 = (i & 15) * 8;
            int gr = brow + r;
            uint4 v = (gr < n) ? *(const uint4*)(X16 + (size_t)gr * 128 + c8)
                               : make_uint4(0u, 0u, 0u, 0u);
            *(uint4*)&As[r][c8] = v;
        }
    } else {
        for (int i = t; i < 64 * 32; i += 256) {
            int r = i >> 5, c4 = (i & 31) * 4;
            int gr = brow + r;
            float4 v = (gr < n) ? *(const float4*)(X + (size_t)gr * 128 + c4)
                                : make_float4(0.f, 0.f, 0.f, 0.f);
            As[r][c4 + 0] = __float2half_rn(v.x);
            As[r][c4 + 1] = __float2half_rn(v.y);
            As[r][c4 + 2] = __float2half_rn(v.z);
            As[r][c4 + 3] = __float2half_rn(v.w);
        }
    }
    // stage W^T (fp16): Wt[n][k] = W[k][n]
    for (int i = t; i < 128 * 32; i += 256) {
        int k = i >> 5, n4 = (i & 31) * 4;
        float4 wv = *(const float4*)(W + k * 128 + n4);
        Wt[n4 + 0][k] = __float2half_rn(wv.x);
        Wt[n4 + 1][k] = __float2half_rn(wv.y);
        Wt[n4 + 2][k] = __float2half_rn(wv.z);
        Wt[n4 + 3][k] = __float2half_rn(wv.w);
    }
    __syncthreads();

    int wid  = t >> 6;
    int lane = t & 63;
    int lrow = lane & 15;
    int lkg  = lane >> 4;        // 0..3
    int r0   = wid * 16;

    f32x4 acc[8] = {};
#pragma unroll
    for (int kk = 0; kk < 128; kk += 32) {
        f16x8 af = *(const f16x8*)&As[r0 + lrow][kk + lkg * 8];
#pragma unroll
        for (int ct = 0; ct < 8; ++ct) {
            f16x8 bf = *(const f16x8*)&Wt[ct * 16 + lrow][kk + lkg * 8];
            acc[ct] = __builtin_amdgcn_mfma_f32_16x16x32_f16(af, bf, acc[ct], 0, 0, 0);
        }
    }

    // H16 store + fused dots
    float sp[4] = {0.f, 0.f, 0.f, 0.f};
    float dp[4] = {0.f, 0.f, 0.f, 0.f};
#pragma unroll
    for (int ct = 0; ct < 8; ++ct) {
        float a_s = as_[ct * 16 + lrow];
        float a_d = ad_[ct * 16 + lrow];
#pragma unroll
        for (int j = 0; j < 4; ++j) {
            sp[j] += acc[ct][j] * a_s;
            dp[j] += acc[ct][j] * a_d;
        }
    }
#pragma unroll
    for (int j = 0; j < 4; ++j) {
        int gr = brow + r0 + lkg * 4 + j;
        if (gr < n) {
#pragma unroll
            for (int ct = 0; ct < 8; ++ct)
                H[(size_t)gr * 128 + ct * 16 + lrow] = __float2half_rn(acc[ct][j]);
        }
    }
#pragma unroll
    for (int off = 1; off < 16; off <<= 1)
#pragma unroll
        for (int j = 0; j < 4; ++j) {
            sp[j] += __shfl_xor(sp[j], off);
            dp[j] += __shfl_xor(dp[j], off);
        }
    if (lrow == 0)
#pragma unroll
        for (int j = 0; j < 4; ++j) {
            int gr = brow + r0 + lkg * 4 + j;
            if (gr < n) { s[gr] = sp[j]; d[gr] = dp[j]; }
        }
}

// ============ bucket-sort CSR build (no global atomics) =============
__global__ __launch_bounds__(512) void bucket_count(const int* __restrict__ dst,
                                                    int* __restrict__ blockcounts) {
    __shared__ int hist[NB];
    int b = blockIdx.x, t = threadIdx.x;
    for (int i = t; i < NB; i += 512) hist[i] = 0;
    __syncthreads();
    int e0 = b * CHUNK, e1 = min(NEDGES, e0 + CHUNK);
    for (int e = e0 + t; e < e1; e += 512)
        atomicAdd(&hist[dst[e] >> 6], 1);
    __syncthreads();
    for (int i = t; i < NB; i += 512)
        blockcounts[i * NCH + b] = hist[i];
}

__global__ __launch_bounds__(NCH) void bucket_scan_a(int* __restrict__ blockcounts,
                                                     int* __restrict__ btotal) {
    int bin = blockIdx.x, t = threadIdx.x;
    int v = blockcounts[bin * NCH + t];
    int incl = v;
#pragma unroll
    for (int off = 1; off < 64; off <<= 1) {
        int u = __shfl_up(incl, off, 64);
        if ((t & 63) >= off) incl += u;
    }
    __shared__ int wsum;
    if (t == 63) wsum = incl;
    __syncthreads();
    int excl = incl - v + ((t >= 64) ? wsum : 0);
    blockcounts[bin * NCH + t] = excl;
    if (t == NCH - 1) btotal[bin] = excl + v;
}

__global__ __launch_bounds__(1024) void bucket_scan_b(const int* __restrict__ btotal,
                                                      int* __restrict__ bbase) {
    __shared__ int ts[2][1024];
    int t = threadIdx.x;
    int b0 = t * 2;
    int c0 = (b0 < NB)     ? btotal[b0]     : 0;
    int c1 = (b0 + 1 < NB) ? btotal[b0 + 1] : 0;
    int sum = c0 + c1;
    ts[0][t] = sum;
    __syncthreads();
    int sb = 0;
    for (int off = 1; off < 1024; off <<= 1) {
        int v = ts[sb][t] + ((t >= off) ? ts[sb][t - off] : 0);
        ts[sb ^ 1][t] = v;
        sb ^= 1;
        __syncthreads();
    }
    int excl = ts[sb][t] - sum;
    if (b0 < NB)     bbase[b0]     = excl;
    if (b0 + 1 < NB) bbase[b0 + 1] = excl + c0;
    if (t == 1023) bbase[NB] = ts[sb][1023];
}

__global__ __launch_bounds__(512) void bucket_scatter(const int* __restrict__ src,
                                                      const int* __restrict__ dst,
                                                      const int* __restrict__ blockcounts,
                                                      const int* __restrict__ bbase,
                                                      int* __restrict__ packed) {
    __shared__ int cur[NB];
    int b = blockIdx.x, t = threadIdx.x;
    for (int i = t; i < NB; i += 512) cur[i] = bbase[i] + blockcounts[i * NCH + b];
    __syncthreads();
    int e0 = b * CHUNK, e1 = min(NEDGES, e0 + CHUNK);
    for (int e = e0 + t; e < e1; e += 512) {
        int dv = dst[e];
        int bin = dv >> 6;
        int p = atomicAdd(&cur[bin], 1);
        packed[p] = ((dv & 63) << 17) | src[e];
    }
}

__global__ __launch_bounds__(256) void bucket_csr(const int* __restrict__ packed,
                                                  const int* __restrict__ bbase,
                                                  int* __restrict__ rowptr,
                                                  int* __restrict__ csr_src) {
    __shared__ int ebuf[EBUF];
    __shared__ int hist[64], cur[64];
    int i = blockIdx.x, t = threadIdx.x;
    int base = bbase[i], cnt = bbase[i + 1] - base;
    bool inl = (cnt <= EBUF);
    if (inl) for (int j = t; j < cnt; j += 256) ebuf[j] = packed[base + j];
    if (t < 64) hist[t] = 0;
    __syncthreads();
    for (int j = t; j < cnt; j += 256) {
        int v = inl ? ebuf[j] : packed[base + j];
        atomicAdd(&hist[v >> 17], 1);
    }
    __syncthreads();
    if (t < 64) {
        int h = hist[t];
        int incl = h;
#pragma unroll
        for (int off = 1; off < 64; off <<= 1) {
            int u = __shfl_up(incl, off, 64);
            if (t >= off) incl += u;
        }
        int ex = incl - h;
        cur[t] = ex;
        int node = i * 64 + t;
        if (node <= NNODES) rowptr[node] = base + ex;
    }
    __syncthreads();
    for (int j = t; j < cnt; j += 256) {
        int v = inl ? ebuf[j] : packed[base + j];
        int off = atomicAdd(&cur[v >> 17], 1);
        csr_src[base + off] = v & 0x1FFFF;
    }
}

// ============ fused gather: softmax + aggregate + bias + relu (+classifier)
// A output fp16 (feeds next layer's MFMA); LAST writes f32 classifier out.
template <bool LAST>
__global__ __launch_bounds__(256) void gat_gather(const int* __restrict__ rowptr,
                                                  const int* __restrict__ csr,
                                                  const float* __restrict__ s,
                                                  const float* __restrict__ d,
                                                  const __half* __restrict__ H,
                                                  const float* __restrict__ bias,
                                                  const float* __restrict__ Wc,
                                                  const float* __restrict__ bc,
                                                  __half* __restrict__ A16,
                                                  float* __restrict__ out, int n) {
    int node = blockIdx.x * 4 + (threadIdx.x >> 6);
    if (node >= n) return;
    int lane = threadIdx.x & 63;
    int half = lane >> 5;
    int pos  = lane & 31;
    int base = rowptr[node];
    int deg  = rowptr[node + 1] - base;
    float dnode = d[node];
    float snode = s[node];

    float4 acc = make_float4(0.f, 0.f, 0.f, 0.f);
    float denom;

    if (deg < 64) {
        int cnt = deg + 1;
        int si  = (lane < deg) ? csr[base + lane] : node;
        float sv = (lane < deg) ? s[si] : snode;
        float lv = leaky02(sv + dnode);
        float lm = (lane < cnt) ? lv : -1e30f;
#pragma unroll
        for (int off = 32; off; off >>= 1) lm = fmaxf(lm, __shfl_xor(lm, off));
        float w = (lane < cnt) ? expf(lv - lm) : 0.f;
        denom = w;
#pragma unroll
        for (int off = 32; off; off >>= 1) denom += __shfl_xor(denom, off);

        int jfull = cnt & ~15;
        for (int j = 0; j < jfull; j += 16) {
            float wk[8]; int sk[8];
#pragma unroll
            for (int k = 0; k < 8; ++k) {
                int ii = j + 2 * k + half;
                wk[k] = __shfl(w, ii);
                sk[k] = __shfl(si, ii);
            }
            H8u hv[8];
#pragma unroll
            for (int k = 0; k < 8; ++k)
                hv[k].u = *(const uint2*)(H + (size_t)sk[k] * 128 + pos * 4);
#pragma unroll
            for (int k = 0; k < 8; ++k) {
                float2 a01 = __half22float2(hv[k].h[0]);
                float2 a23 = __half22float2(hv[k].h[1]);
                acc.x += wk[k] * a01.x;
                acc.y += wk[k] * a01.y;
                acc.z += wk[k] * a23.x;
                acc.w += wk[k] * a23.y;
            }
        }
        int rem = cnt - jfull;              // wave-uniform tail
        int kmax = (rem + 1) >> 1;
        for (int k = 0; k < kmax; ++k) {
            int ii = jfull + 2 * k + half;
            float wv = __shfl(w, ii);
            int   sv2 = __shfl(si, ii);
            H8u hv;
            hv.u = *(const uint2*)(H + (size_t)sv2 * 128 + pos * 4);
            float2 a01 = __half22float2(hv.h[0]);
            float2 a23 = __half22float2(hv.h[1]);
            acc.x += wv * a01.x;
            acc.y += wv * a01.y;
            acc.z += wv * a23.x;
            acc.w += wv * a23.y;
        }
    } else {
        float m = -1e30f;
        for (int c = 0; c <= deg; c += 64) {
            int idx = c + lane;
            float lv = -1e30f;
            if (idx < deg)       lv = leaky02(s[csr[base + idx]] + dnode);
            else if (idx == deg) lv = leaky02(snode + dnode);
            m = fmaxf(m, lv);
        }
#pragma unroll
        for (int off = 32; off; off >>= 1) m = fmaxf(m, __shfl_xor(m, off));
        denom = 0.f;
        for (int c = 0; c <= deg; c += 64) {
            int idx = c + lane;
            int cnt = min(64, deg + 1 - c);
            int si = (idx < deg) ? csr[base + idx] : node;
            float w = 0.f;
            if (idx < deg)       w = expf(leaky02(s[si] + dnode) - m);
            else if (idx == deg) w = expf(leaky02(snode + dnode) - m);
            denom += w;
            int cnt16 = (cnt + 15) & ~15;
            for (int j = 0; j < cnt16; j += 16) {
                float wk[8]; int sk[8];
#pragma unroll
                for (int k = 0; k < 8; ++k) {
                    int ii = j + 2 * k + half;
                    wk[k] = __shfl(w, ii);
                    sk[k] = __shfl(si, ii);
                }
                H8u hv[8];
#pragma unroll
                for (int k = 0; k < 8; ++k)
                    hv[k].u = *(const uint2*)(H + (size_t)sk[k] * 128 + pos * 4);
#pragma unroll
                for (int k = 0; k < 8; ++k) {
                    float2 a01 = __half22float2(hv[k].h[0]);
                    float2 a23 = __half22float2(hv[k].h[1]);
                    acc.x += wk[k] * a01.x;
                    acc.y += wk[k] * a01.y;
                    acc.z += wk[k] * a23.x;
                    acc.w += wk[k] * a23.y;
                }
            }
        }
#pragma unroll
        for (int off = 32; off; off >>= 1) denom += __shfl_xor(denom, off);
    }

    acc.x += __shfl_xor(acc.x, 32);
    acc.y += __shfl_xor(acc.y, 32);
    acc.z += __shfl_xor(acc.z, 32);
    acc.w += __shfl_xor(acc.w, 32);
    if (half == 0) {
        float inv = 1.f / denom;
        float4 o;
        o.x = fmaxf(acc.x * inv + bias[pos * 4 + 0], 0.f);
        o.y = fmaxf(acc.y * inv + bias[pos * 4 + 1], 0.f);
        o.z = fmaxf(acc.z * inv + bias[pos * 4 + 2], 0.f);
        o.w = fmaxf(acc.w * inv + bias[pos * 4 + 3], 0.f);
        if (!LAST) {
            H8u pk;
            pk.h[0] = __floats2half2_rn(o.x, o.y);
            pk.h[1] = __floats2half2_rn(o.z, o.w);
            *(uint2*)(A16 + (size_t)node * 128 + pos * 4) = pk.u;
        } else {
            float c0v = o.x * Wc[(pos * 4 + 0) * 2] + o.y * Wc[(pos * 4 + 1) * 2] +
                        o.z * Wc[(pos * 4 + 2) * 2] + o.w * Wc[(pos * 4 + 3) * 2];
            float c1v = o.x * Wc[(pos * 4 + 0) * 2 + 1] + o.y * Wc[(pos * 4 + 1) * 2 + 1] +
                        o.z * Wc[(pos * 4 + 2) * 2 + 1] + o.w * Wc[(pos * 4 + 3) * 2 + 1];
#pragma unroll
            for (int off = 16; off; off >>= 1) {
                c0v += __shfl_xor(c0v, off);
                c1v += __shfl_xor(c1v, off);
            }
            if (pos == 0) {
                out[(size_t)node * 2 + 0] = c0v + bc[0];
                out[(size_t)node * 2 + 1] = c1v + bc[1];
            }
        }
    }
}

extern "C" void kernel_launch(void* const* d_in, const int* in_sizes, int n_in,
                              void* d_out, int out_size, void* d_ws, size_t ws_size,
                              hipStream_t stream) {
    const float* x   = (const float*)d_in[0];
    const int*   ei  = (const int*)d_in[1];
    const int*   src = ei;
    const int*   dst = ei + NEDGES;
    const float* Ws[3]  = {(const float*)d_in[2], (const float*)d_in[6], (const float*)d_in[10]};
    const float* ass[3] = {(const float*)d_in[3], (const float*)d_in[7], (const float*)d_in[11]};
    const float* ads[3] = {(const float*)d_in[4], (const float*)d_in[8], (const float*)d_in[12]};
    const float* bs[3]  = {(const float*)d_in[5], (const float*)d_in[9], (const float*)d_in[13]};
    const float* Wc = (const float*)d_in[14];
    const float* bc = (const float*)d_in[15];
    float* out = (float*)d_out;

    const int n = NNODES;

    // ---- workspace (~66 MB): h16 | a16 | s | d | int tail ----
    __half* h16  = (__half*)d_ws;                       // N*128 fp16
    __half* a16  = h16 + (size_t)n * DIM;               // N*128 fp16
    float*  sbuf = (float*)(a16 + (size_t)n * DIM);     // N
    float*  dbuf = sbuf + n;                            // N
    int*    rowptr      = (int*)(dbuf + n);             // N+1
    int*    csr_src     = rowptr + n + 1;               // E
    int*    packed      = csr_src + NEDGES;             // E
    int*    blockcounts = packed + NEDGES;              // NB*NCH
    int*    bbase       = blockcounts + NB * NCH;       // NB+1
    int*    btotal      = bbase + NB + 1;               // NB

    const int g64         = (n + 63) / 64;
    const int gather_grid = (n + 3) / 4;

    // ---- bucket-sort CSR build (once, reused by all 3 layers) ----
    bucket_count<<<NCH, 512, 0, stream>>>(dst, blockcounts);
    bucket_scan_a<<<NB, NCH, 0, stream>>>(blockcounts, btotal);
    bucket_scan_b<<<1, 1024, 0, stream>>>(btotal, bbase);
    bucket_scatter<<<NCH, 512, 0, stream>>>(src, dst, blockcounts, bbase, packed);
    bucket_csr<<<NB, 256, 0, stream>>>(packed, bbase, rowptr, csr_src);

    // ---- 3 GAT layers ----
    for (int layer = 0; layer < 3; ++layer) {
        if (layer == 0)
            gemm_mfma<false><<<g64, 256, 0, stream>>>(x, a16, Ws[0], ass[0], ads[0],
                                                      h16, sbuf, dbuf, n);
        else
            gemm_mfma<true><<<g64, 256, 0, stream>>>(x, a16, Ws[layer], ass[layer], ads[layer],
                                                     h16, sbuf, dbuf, n);
        if (layer == 2)
            gat_gather<true><<<gather_grid, 256, 0, stream>>>(
                rowptr, csr_src, sbuf, dbuf, h16, bs[layer], Wc, bc, a16, out, n);
        else
            gat_gather<false><<<gather_grid, 256, 0, stream>>>(
                rowptr, csr_src, sbuf, dbuf, h16, bs[layer], Wc, bc, a16, out, n);
    }
}